// Round 6
// baseline (252.327 us; speedup 1.0000x reference)
//
#include <hip/hip_runtime.h>

typedef __bf16 bf16_t;
typedef __bf16 bf16x8 __attribute__((ext_vector_type(8)));
typedef __bf16 bf16x4 __attribute__((ext_vector_type(4)));
typedef float  f32x4  __attribute__((ext_vector_type(4)));

// ---------------------------------------------------------------------------
// Workspace layout (floats unless noted):
//   A    : [4096][256] f32  (xf @ W1[0:26])                        4 MB
//   C    : [4096][256] f32  (xf @ W1[26:52] + qst @ W1[52:180]+b1) 4 MB
//   Wt   : 3 x [256][256] bf16 in MFMA A-fragment layout:
//          [mat][tile16(no>>4)][ks(k>>5)][lane(q*16+r)][e], no=n-row,
//          q=(k>>3)&3, r=no&15, e=k&7.  Per-(tile,ks) wave load is one
//          coalesced 1 KB transaction.                             384 KB
//   part : [4096][256] f32  per-block partial pair-sums            4 MB
//
// h in LDS uses the matching B-fragment-linear layout:
//   h[chunk = mt*8+ks][lane = q*16+r][e]  <->  h[m = mt*16+r][k = ks*32+q*8+e]
// so ALL LDS reads/writes are lane-contiguous -> zero bank conflicts.
//
// Round 6: occupancy doubling.  r4/r5 pinned the invariant
// MfmaUtil x dur ~= 43us (the MFMA floor) with HBM/LDS/L2 all idle ->
// pure duty-cycle wall at 2 waves/SIMD (both LDS- and register-bound).
// This round: M=64 per block (one i), acc[4][4] = 64 AGPR + ~64 arch VGPR,
// 32 KB LDS -> 4 waves/SIMD from 4 independent blocks.  r1 tried this
// geometry and regressed; its three defects are now individually fixed:
// scattered W loads (fragment layout), LDS conflicts (fragment layout),
// and the xg atomicAdd storm (replaced by plain partial-sum stores + a
// cheap reduction in the f-kernel).
// ---------------------------------------------------------------------------

// ---------------- prep: A, C, weight fragment-relayout ----------------------
__global__ __launch_bounds__(256) void rn_prep_kernel(
    const float* __restrict__ x, const float* __restrict__ qst,
    const float* __restrict__ g1w, const float* __restrict__ g1b,
    const float* __restrict__ g2w, const float* __restrict__ g3w,
    const float* __restrict__ g4w,
    float* __restrict__ A, float* __restrict__ C,
    bf16_t* __restrict__ Wt)
{
  __shared__ float T[64][65];   // transpose tile (only used by that branch)
  int blk = blockIdx.x;
  int n   = threadIdx.x;  // 0..255
  if (blk < 256) {
    // block = (b, jg): rows jg*16 .. jg*16+15 of batch b; thread = output col n
    int b  = blk >> 2;
    int jg = (blk & 3) * 16;
    float accQ = g1b[n];
    const float* qb = qst + b * 128;
    #pragma unroll 8
    for (int qi = 0; qi < 128; ++qi)
      accQ += qb[qi] * g1w[(52 + qi) * 256 + n];

    float w24 = g1w[24 * 256 + n], w25 = g1w[25 * 256 + n];
    float w50 = g1w[50 * 256 + n], w51 = g1w[51 * 256 + n];
    float accA[16], accC[16];
    #pragma unroll
    for (int t = 0; t < 16; ++t) {
      int j = jg + t;
      // faithful to (a/d - d/2)/(d/2.0) float arithmetic, d=8 (exact pow2 ops)
      float cx = ((float)j * 0.125f - 4.0f) * 0.25f;
      float cy = ((float)(j & 7) - 4.0f) * 0.25f;
      accA[t] = cx * w24 + cy * w25;
      accC[t] = accQ + cx * w50 + cy * w51;
    }
    for (int c = 0; c < 24; ++c) {
      float wa = g1w[c * 256 + n];
      float wc = g1w[(26 + c) * 256 + n];
      const float* xc = x + (b * 24 + c) * 64 + jg;
      #pragma unroll
      for (int t = 0; t < 16; ++t) {
        float xv = xc[t];   // uniform per thread -> scalar load
        accA[t] += xv * wa;
        accC[t] += xv * wc;
      }
    }
    #pragma unroll
    for (int t = 0; t < 16; ++t) {
      A[(b * 64 + jg + t) * 256 + n] = accA[t];
      C[(b * 64 + jg + t) * 256 + n] = accC[t];
    }
  } else {
    // LDS-tiled transpose: g2/g3/g4 [in(k)][out(no)] f32 -> bf16 fragment
    // layout: element (no,k) -> [(no>>4)*8 + (k>>5)][((k>>3)&3)*16 + (no&15)][k&7]
    int t   = blk - 256;
    int mat = t >> 4;                 // 0..2
    int tl  = t & 15;                 // 4x4 tiles of 64x64
    int kt  = (tl & 3) * 64;
    int nt_ = (tl >> 2) * 64;
    const float* W = (mat == 0) ? g2w : (mat == 1 ? g3w : g4w);
    int lane = n & 63, w = n >> 6;
    #pragma unroll
    for (int it = 0; it < 16; ++it) {
      int kl = w * 16 + it;
      T[kl][lane] = W[(kt + kl) * 256 + nt_ + lane];   // coalesced 256B/wave
    }
    __syncthreads();
    #pragma unroll
    for (int it = 0; it < 16; ++it) {
      int nl  = w * 16 + it;
      int no  = nt_ + nl;     // output-neuron index
      int k   = kt + lane;    // input index
      int tile = no >> 4, rr = no & 15;
      int ksI  = k >> 5,  qI = (k >> 3) & 3, e = k & 7;
      int idx  = ((tile * 8 + ksI) * 64 + qI * 16 + rr) * 8 + e;
      Wt[mat * 65536 + idx] = (bf16_t)T[lane][nl];
    }
  }
}

// ---------------- main fused g-MLP (layers 2..4) + pair partial-sum --------
// one block per (b, i): M = 64 rows, N = K = 256, 4 waves.
// Wave w owns n-rows [w*64, w*64+64) (nt=0..3) and all 64 m-rows (mt=0..3).
// Per ks: 4 wf global (1 KB contiguous, L1/L2-shared) + 4 hf LDS
// (lane-contiguous, conflict-free) -> 16 MFMA.
// acc[4][4] = 64 AGPR + ~64 arch VGPR -> 4 waves/SIMD (launch_bounds 256,4),
// 4 blocks/CU; the 4 waves on a SIMD come from 4 barrier-independent blocks,
// so they cover each other's load/epilogue/barrier phases.
__global__ __launch_bounds__(256, 4) void rn_main_kernel(
    const float* __restrict__ A, const float* __restrict__ C,
    const bf16_t* __restrict__ Wt,
    const float* __restrict__ g2b, const float* __restrict__ g3b,
    const float* __restrict__ g4b,
    float* __restrict__ part)
{
  __shared__ bf16_t h[16384];   // 32 KB: [chunk=mt*8+ks][lane][8]

  int tid  = threadIdx.x;
  int bx0  = blockIdx.x;
  // bijective XCD swizzle (4096 % 8 == 0): 512 consecutive work-units per
  // XCD -> the 64 blocks sharing a batch b stay on one XCD's L2 (A locality)
  int bx   = (bx0 & 7) * 512 + (bx0 >> 3);
  int b    = bx >> 6;          // batch
  int i    = bx & 63;          // i-object
  int lane = tid & 63;
  int wave = tid >> 6;
  int r    = lane & 15;        // 16-dim index within MFMA tile
  int q    = lane >> 4;        // quad: k-run selector / D-row group

  // ---- build h rows into fragment-linear layout ----
  // wave w builds chunks (mt=w, ks=it): thread (q,r) -> m-row j = w*16+r,
  // k-run = it*32+q*8.  LDS writes are lane-contiguous 1 KB per instr.
  {
    const float* Ab = A + (size_t)b * 64 * 256;
    const float* Cr = C + ((size_t)b * 64 + i) * 256;
    int j = wave * 16 + r;
    #pragma unroll
    for (int it = 0; it < 8; ++it) {
      int k0 = it * 32 + q * 8;
      const float4 a0 = *(const float4*)(Ab + j * 256 + k0);
      const float4 a1 = *(const float4*)(Ab + j * 256 + k0 + 4);
      const float4 c0 = *(const float4*)(Cr + k0);
      const float4 c1 = *(const float4*)(Cr + k0 + 4);
      bf16x8 v;
      v[0] = (bf16_t)fmaxf(a0.x + c0.x, 0.f);
      v[1] = (bf16_t)fmaxf(a0.y + c0.y, 0.f);
      v[2] = (bf16_t)fmaxf(a0.z + c0.z, 0.f);
      v[3] = (bf16_t)fmaxf(a0.w + c0.w, 0.f);
      v[4] = (bf16_t)fmaxf(a1.x + c1.x, 0.f);
      v[5] = (bf16_t)fmaxf(a1.y + c1.y, 0.f);
      v[6] = (bf16_t)fmaxf(a1.z + c1.z, 0.f);
      v[7] = (bf16_t)fmaxf(a1.w + c1.w, 0.f);
      *(bf16x8*)&h[((wave * 8 + it) * 64 + lane) * 8] = v;
    }
  }

  for (int L = 0; L < 3; ++L) {
    __syncthreads();           // h (build or previous epilogue) visible
    // this wave's 4 W tiles: tile = wave*4 + nt  -> base offset wave*16384
    const bf16_t* Wl   = Wt + L * 65536 + wave * 16384;
    const float*  bias = (L == 0) ? g2b : (L == 1) ? g3b : g4b;

    f32x4 acc[4][4];           // [nt][mt]
    #pragma unroll
    for (int nt = 0; nt < 4; ++nt)
      #pragma unroll
      for (int mt = 0; mt < 4; ++mt)
        #pragma unroll
        for (int e = 0; e < 4; ++e) acc[nt][mt][e] = 0.f;

    #pragma unroll
    for (int ks = 0; ks < 8; ++ks) {
      bf16x8 wf[4], hf[4];
      #pragma unroll
      for (int nt = 0; nt < 4; ++nt)
        wf[nt] = *(const bf16x8*)&Wl[((nt * 8 + ks) * 64 + lane) * 8];
      #pragma unroll
      for (int mt = 0; mt < 4; ++mt)
        hf[mt] = *(const bf16x8*)&h[((mt * 8 + ks) * 64 + lane) * 8];
      #pragma unroll
      for (int nt = 0; nt < 4; ++nt)
        #pragma unroll
        for (int mt = 0; mt < 4; ++mt)
          acc[nt][mt] = __builtin_amdgcn_mfma_f32_16x16x32_bf16(
              wf[nt], hf[mt], acc[nt][mt], 0, 0, 0);
    }

    __syncthreads();           // all reads of h done -> safe to overwrite

    if (L < 2) {
      // D value (nt,mt,e): n = wave*64+nt*16+q*4+e (next layer's k),
      // m = mt*16+r.  Fragment-linear write-back into h.
      #pragma unroll
      for (int nt = 0; nt < 4; ++nt) {
        int k0  = wave * 64 + nt * 16 + q * 4;
        float4 bv = *(const float4*)&bias[k0];
        int ks_ = k0 >> 5, rem = k0 & 31;
        int qp  = rem >> 3, e0 = rem & 7;     // e0 in {0,4}
        #pragma unroll
        for (int mt = 0; mt < 4; ++mt) {
          bf16x4 v;
          v[0] = (bf16_t)fmaxf(acc[nt][mt][0] + bv.x, 0.f);
          v[1] = (bf16_t)fmaxf(acc[nt][mt][1] + bv.y, 0.f);
          v[2] = (bf16_t)fmaxf(acc[nt][mt][2] + bv.z, 0.f);
          v[3] = (bf16_t)fmaxf(acc[nt][mt][3] + bv.w, 0.f);
          int off = ((mt * 8 + ks_) * 64 + qp * 16 + r) * 8 + e0;
          *(bf16x4*)&h[off] = v;
        }
      }
    } else {
      // last layer: bias+relu fp32, sum over the 64 m-rows (mt in-register,
      // then the 16 r-lanes), then PLAIN float4 store of this block's
      // partial into part[bx][n] -- no atomics (r1's storm: 158 MB WRITE).
      #pragma unroll
      for (int nt = 0; nt < 4; ++nt) {
        int k0 = wave * 64 + nt * 16 + q * 4;
        float4 bv = *(const float4*)&bias[k0];
        float p0 = 0.f, p1 = 0.f, p2 = 0.f, p3 = 0.f;
        #pragma unroll
        for (int mt = 0; mt < 4; ++mt) {
          p0 += fmaxf(acc[nt][mt][0] + bv.x, 0.f);
          p1 += fmaxf(acc[nt][mt][1] + bv.y, 0.f);
          p2 += fmaxf(acc[nt][mt][2] + bv.z, 0.f);
          p3 += fmaxf(acc[nt][mt][3] + bv.w, 0.f);
        }
        #pragma unroll
        for (int d = 1; d < 16; d <<= 1) {
          p0 += __shfl_xor(p0, d, 64);
          p1 += __shfl_xor(p1, d, 64);
          p2 += __shfl_xor(p2, d, 64);
          p3 += __shfl_xor(p3, d, 64);
        }
        if (r == 0) {
          float4 pv = make_float4(p0, p1, p2, p3);
          *(float4*)&part[(size_t)bx * 256 + k0] = pv;
        }
      }
    }
  }
}

// ---------------- partial reduce + f-MLP + log_softmax (tiny, fp32) --------
__global__ __launch_bounds__(256) void rn_f_kernel(
    const float* __restrict__ part,
    const float* __restrict__ f1w, const float* __restrict__ f1b,
    const float* __restrict__ f2w, const float* __restrict__ f2b,
    const float* __restrict__ f3w, const float* __restrict__ f3b,
    float* __restrict__ out)
{
  __shared__ float xs[256], t1[256], t2[256], lg[28], lse[1];
  int b = blockIdx.x, tid = threadIdx.x;
  // reduce the 64 per-i partials of batch b (coalesced 1 KB/wave per iter)
  float s = 0.f;
  const float* pb = part + (size_t)b * 64 * 256;
  #pragma unroll 8
  for (int i = 0; i < 64; ++i) s += pb[i * 256 + tid];
  xs[tid] = s;
  __syncthreads();
  float acc = f1b[tid];
  for (int k = 0; k < 256; ++k) acc += xs[k] * f1w[k * 256 + tid];
  t1[tid] = fmaxf(acc, 0.f);
  __syncthreads();
  acc = f2b[tid];
  for (int k = 0; k < 256; ++k) acc += t1[k] * f2w[k * 256 + tid];
  t2[tid] = fmaxf(acc, 0.f);
  __syncthreads();
  if (tid < 28) {
    float a2 = f3b[tid];
    for (int k = 0; k < 256; ++k) a2 += t2[k] * f3w[k * 28 + tid];
    lg[tid] = a2;
  }
  __syncthreads();
  if (tid == 0) {
    float m = lg[0];
    for (int j = 1; j < 28; ++j) m = fmaxf(m, lg[j]);
    float se = 0.f;
    for (int j = 0; j < 28; ++j) se += expf(lg[j] - m);
    lse[0] = m + logf(se);
  }
  __syncthreads();
  if (tid < 28) out[b * 28 + tid] = lg[tid] - lse[0];
}

// ---------------------------------------------------------------------------
extern "C" void kernel_launch(void* const* d_in, const int* in_sizes, int n_in,
                              void* d_out, int out_size, void* d_ws, size_t ws_size,
                              hipStream_t stream) {
  (void)in_sizes; (void)n_in; (void)out_size; (void)ws_size;
  const float* x   = (const float*)d_in[0];
  const float* qst = (const float*)d_in[1];
  const float* g1w = (const float*)d_in[2];
  const float* g1b = (const float*)d_in[3];
  const float* g2w = (const float*)d_in[4];
  const float* g2b = (const float*)d_in[5];
  const float* g3w = (const float*)d_in[6];
  const float* g3b = (const float*)d_in[7];
  const float* g4w = (const float*)d_in[8];
  const float* g4b = (const float*)d_in[9];
  const float* f1w = (const float*)d_in[10];
  const float* f1b = (const float*)d_in[11];
  const float* f2w = (const float*)d_in[12];
  const float* f2b = (const float*)d_in[13];
  const float* f3w = (const float*)d_in[14];
  const float* f3b = (const float*)d_in[15];
  float* out = (float*)d_out;

  float*  A    = (float*)d_ws;
  float*  C    = A + 4096 * 256;
  bf16_t* Wt   = (bf16_t*)(C + 4096 * 256);
  float*  part = (float*)((char*)Wt + 3 * 65536 * sizeof(bf16_t));

  rn_prep_kernel<<<256 + 48, 256, 0, stream>>>(
      x, qst, g1w, g1b, g2w, g3w, g4w, A, C, Wt);
  rn_main_kernel<<<4096, 256, 0, stream>>>(A, C, Wt, g2b, g3b, g4b, part);
  rn_f_kernel<<<64, 256, 0, stream>>>(part, f1w, f1b, f2w, f2b, f3w, f3b, out);
}

// Round 8
// 251.327 us; speedup vs baseline: 1.0040x; 1.0040x over previous
//
#include <hip/hip_runtime.h>

typedef __bf16 bf16_t;
typedef __bf16 bf16x8 __attribute__((ext_vector_type(8)));
typedef __bf16 bf16x4 __attribute__((ext_vector_type(4)));
typedef float  f32x4  __attribute__((ext_vector_type(4)));

// ---------------------------------------------------------------------------
// Workspace layout (floats unless noted):
//   A    : [4096][256] f32  (xf @ W1[0:26])                        4 MB
//   C    : [4096][256] f32  (xf @ W1[26:52] + qst @ W1[52:180]+b1) 4 MB
//   Wt   : 3 x [256][256] bf16 in MFMA A-fragment layout:
//          [mat][tile16(no>>4)][ks(k>>5)][lane(q*16+r)][e], no=n-row,
//          q=(k>>3)&3, r=no&15, e=k&7.  Per-(tile,ks) wave load is one
//          coalesced 1 KB transaction.                             384 KB
//   part : [2048][256] f32  per-block partial pair-sums            2 MB
//
// h in LDS uses the matching B-fragment-linear layout:
//   h[chunk = mt*8+ks][lane = q*16+r][e]  <->  h[m = mt*16+r][k = ks*32+q*8+e]
// -> zero bank conflicts by construction.
//
// Round 8 (= round 7 resubmit; r7 was an infra failure, no data):
// register-stationary W at 1 wave/SIMD.
// Evidence: r4 (2w/SIMD locked) = r6 (4w/SIMD independent) = ~140us,
// MfmaUtil 30, HBM/LDS idle -> the cap is the shared vector-memory (TCP/L1)
// path carrying per-ks W fragment loads (W working set 128-512 KB/CU
// thrashes the 32 KB L1; ~16-32 TCP cyc per 1 KB load; traffic scales with
// blocks, canceling TLP).  Fix: each wave preloads its 32 KB W slice into
// 128 VGPRs once per layer (r2's plan, which spilled at the 256-reg budget
// of 2 waves/SIMD).  At __launch_bounds__(256,1) the budget is 512:
// wreg 128 + acc 128 (AGPR) + hf 32 + temps ~40 = ~330 -> no spill.
// Inner loop = 8 LDS reads + 32 MFMA, zero global. MFMA becomes top pipe.
// ---------------------------------------------------------------------------

// ---------------- prep: A, C, weight fragment-relayout ----------------------
__global__ __launch_bounds__(256) void rn_prep_kernel(
    const float* __restrict__ x, const float* __restrict__ qst,
    const float* __restrict__ g1w, const float* __restrict__ g1b,
    const float* __restrict__ g2w, const float* __restrict__ g3w,
    const float* __restrict__ g4w,
    float* __restrict__ A, float* __restrict__ C,
    bf16_t* __restrict__ Wt)
{
  __shared__ float T[64][65];   // transpose tile (only used by that branch)
  int blk = blockIdx.x;
  int n   = threadIdx.x;  // 0..255
  if (blk < 256) {
    // block = (b, jg): rows jg*16 .. jg*16+15 of batch b; thread = output col n
    int b  = blk >> 2;
    int jg = (blk & 3) * 16;
    float accQ = g1b[n];
    const float* qb = qst + b * 128;
    #pragma unroll 8
    for (int qi = 0; qi < 128; ++qi)
      accQ += qb[qi] * g1w[(52 + qi) * 256 + n];

    float w24 = g1w[24 * 256 + n], w25 = g1w[25 * 256 + n];
    float w50 = g1w[50 * 256 + n], w51 = g1w[51 * 256 + n];
    float accA[16], accC[16];
    #pragma unroll
    for (int t = 0; t < 16; ++t) {
      int j = jg + t;
      // faithful to (a/d - d/2)/(d/2.0) float arithmetic, d=8 (exact pow2 ops)
      float cx = ((float)j * 0.125f - 4.0f) * 0.25f;
      float cy = ((float)(j & 7) - 4.0f) * 0.25f;
      accA[t] = cx * w24 + cy * w25;
      accC[t] = accQ + cx * w50 + cy * w51;
    }
    for (int c = 0; c < 24; ++c) {
      float wa = g1w[c * 256 + n];
      float wc = g1w[(26 + c) * 256 + n];
      const float* xc = x + (b * 24 + c) * 64 + jg;
      #pragma unroll
      for (int t = 0; t < 16; ++t) {
        float xv = xc[t];   // uniform per thread -> scalar load
        accA[t] += xv * wa;
        accC[t] += xv * wc;
      }
    }
    #pragma unroll
    for (int t = 0; t < 16; ++t) {
      A[(b * 64 + jg + t) * 256 + n] = accA[t];
      C[(b * 64 + jg + t) * 256 + n] = accC[t];
    }
  } else {
    // LDS-tiled transpose: g2/g3/g4 [in(k)][out(no)] f32 -> bf16 fragment
    // layout: element (no,k) -> [(no>>4)*8 + (k>>5)][((k>>3)&3)*16 + (no&15)][k&7]
    int t   = blk - 256;
    int mat = t >> 4;                 // 0..2
    int tl  = t & 15;                 // 4x4 tiles of 64x64
    int kt  = (tl & 3) * 64;
    int nt_ = (tl >> 2) * 64;
    const float* W = (mat == 0) ? g2w : (mat == 1 ? g3w : g4w);
    int lane = n & 63, w = n >> 6;
    #pragma unroll
    for (int it = 0; it < 16; ++it) {
      int kl = w * 16 + it;
      T[kl][lane] = W[(kt + kl) * 256 + nt_ + lane];   // coalesced 256B/wave
    }
    __syncthreads();
    #pragma unroll
    for (int it = 0; it < 16; ++it) {
      int nl  = w * 16 + it;
      int no  = nt_ + nl;     // output-neuron index
      int k   = kt + lane;    // input index
      int tile = no >> 4, rr = no & 15;
      int ksI  = k >> 5,  qI = (k >> 3) & 3, e = k & 7;
      int idx  = ((tile * 8 + ksI) * 64 + qI * 16 + rr) * 8 + e;
      Wt[mat * 65536 + idx] = (bf16_t)T[lane][nl];
    }
  }
}

// ---------------- main fused g-MLP (layers 2..4) + pair partial-sum --------
// one block per (b, i-pair): M = 128 rows (2 i x 64 j), N = K = 256, 4 waves.
// Wave w owns n-rows [w*64, w*64+64) (nt=0..3) and ALL 128 m-rows
// (mt=0..7: h0 for mt<4, h1 for mt>=4).
// Per layer: preload the wave's 32 KB W slice into wreg[4][8] (128 VGPR,
// 32 coalesced 1 KB loads, issued before the layer barrier); then per ks:
// 8 hf LDS reads (lane-contiguous, conflict-free) + 32 MFMA.  No global
// loads in the K-loop.  acc[4][8] = 128 AGPR.  1 wave/SIMD (512-reg budget).
__global__ __launch_bounds__(256, 1) void rn_main_kernel(
    const float* __restrict__ A, const float* __restrict__ C,
    const bf16_t* __restrict__ Wt,
    const float* __restrict__ g2b, const float* __restrict__ g3b,
    const float* __restrict__ g4b,
    float* __restrict__ part)
{
  __shared__ bf16_t h0[16384];   // 32 KB: [chunk=mt*8+ks][lane][8]
  __shared__ bf16_t h1[16384];   // 32 KB

  int tid  = threadIdx.x;
  int bx0  = blockIdx.x;
  // bijective XCD swizzle (2048 % 8 == 0): 256 consecutive work-units per
  // XCD -> the 32 blocks sharing a batch b stay on one XCD's L2
  int bx   = (bx0 & 7) * 256 + (bx0 >> 3);
  int b    = bx >> 5;          // batch
  int ip   = bx & 31;          // i-pair: i = 2*ip, 2*ip+1
  int lane = tid & 63;
  int wave = tid >> 6;
  int r    = lane & 15;        // 16-dim index within MFMA tile
  int q    = lane >> 4;        // quad: k-run selector / D-row group

  // ---- build h rows into fragment-linear layout ----
  // wave w builds chunks (mt=w, ks=it): thread (q,r) -> m-row j = w*16+r,
  // k-run = it*32+q*8.  LDS writes are lane-contiguous 1 KB per instr.
  {
    const float* Ab = A + (size_t)b * 64 * 256;
    const float* Cr = C + ((size_t)b * 64 + ip * 2) * 256;
    int j = wave * 16 + r;
    #pragma unroll
    for (int it = 0; it < 8; ++it) {
      int k0 = it * 32 + q * 8;
      const float4 a0  = *(const float4*)(Ab + j * 256 + k0);
      const float4 a1  = *(const float4*)(Ab + j * 256 + k0 + 4);
      const float4 c00 = *(const float4*)(Cr + k0);
      const float4 c01 = *(const float4*)(Cr + k0 + 4);
      const float4 c10 = *(const float4*)(Cr + 256 + k0);
      const float4 c11 = *(const float4*)(Cr + 256 + k0 + 4);
      bf16x8 v0, v1;
      v0[0] = (bf16_t)fmaxf(a0.x + c00.x, 0.f);
      v0[1] = (bf16_t)fmaxf(a0.y + c00.y, 0.f);
      v0[2] = (bf16_t)fmaxf(a0.z + c00.z, 0.f);
      v0[3] = (bf16_t)fmaxf(a0.w + c00.w, 0.f);
      v0[4] = (bf16_t)fmaxf(a1.x + c01.x, 0.f);
      v0[5] = (bf16_t)fmaxf(a1.y + c01.y, 0.f);
      v0[6] = (bf16_t)fmaxf(a1.z + c01.z, 0.f);
      v0[7] = (bf16_t)fmaxf(a1.w + c01.w, 0.f);
      v1[0] = (bf16_t)fmaxf(a0.x + c10.x, 0.f);
      v1[1] = (bf16_t)fmaxf(a0.y + c10.y, 0.f);
      v1[2] = (bf16_t)fmaxf(a0.z + c10.z, 0.f);
      v1[3] = (bf16_t)fmaxf(a0.w + c10.w, 0.f);
      v1[4] = (bf16_t)fmaxf(a1.x + c11.x, 0.f);
      v1[5] = (bf16_t)fmaxf(a1.y + c11.y, 0.f);
      v1[6] = (bf16_t)fmaxf(a1.z + c11.z, 0.f);
      v1[7] = (bf16_t)fmaxf(a1.w + c11.w, 0.f);
      int off = ((wave * 8 + it) * 64 + lane) * 8;
      *(bf16x8*)&h0[off] = v0;
      *(bf16x8*)&h1[off] = v1;
    }
  }

  for (int L = 0; L < 3; ++L) {
    // ---- preload this wave's W slice (32 KB -> 128 VGPR), BEFORE the
    // barrier so the load latency hides under the sync + other waves' tails.
    const bf16_t* Wl = Wt + L * 65536 + wave * 16384;
    bf16x8 wreg[4][8];
    #pragma unroll
    for (int nt = 0; nt < 4; ++nt)
      #pragma unroll
      for (int ks = 0; ks < 8; ++ks)
        wreg[nt][ks] = *(const bf16x8*)&Wl[((nt * 8 + ks) * 64 + lane) * 8];

    const float* bias = (L == 0) ? g2b : (L == 1) ? g3b : g4b;

    __syncthreads();           // h (build or previous epilogue) visible

    f32x4 acc[4][8];           // [nt][mt]
    #pragma unroll
    for (int nt = 0; nt < 4; ++nt)
      #pragma unroll
      for (int mt = 0; mt < 8; ++mt)
        #pragma unroll
        for (int e = 0; e < 4; ++e) acc[nt][mt][e] = 0.f;

    #pragma unroll
    for (int ks = 0; ks < 8; ++ks) {
      bf16x8 hf[8];
      #pragma unroll
      for (int mt = 0; mt < 8; ++mt) {
        const bf16_t* hb = (mt < 4) ? h0 : h1;
        hf[mt] = *(const bf16x8*)&hb[(((mt & 3) * 8 + ks) * 64 + lane) * 8];
      }
      #pragma unroll
      for (int nt = 0; nt < 4; ++nt)
        #pragma unroll
        for (int mt = 0; mt < 8; ++mt)
          acc[nt][mt] = __builtin_amdgcn_mfma_f32_16x16x32_bf16(
              wreg[nt][ks], hf[mt], acc[nt][mt], 0, 0, 0);
    }

    __syncthreads();           // all reads of h done -> safe to overwrite

    if (L < 2) {
      // D value (nt,mt,e): n = wave*64+nt*16+q*4+e (next layer's k),
      // m = mt*16+r (mt<4 -> h0, else h1).  Fragment-linear write-back.
      #pragma unroll
      for (int nt = 0; nt < 4; ++nt) {
        int k0  = wave * 64 + nt * 16 + q * 4;
        float4 bv = *(const float4*)&bias[k0];
        int ks_ = k0 >> 5, rem = k0 & 31;
        int qp  = rem >> 3, e0 = rem & 7;     // e0 in {0,4}
        #pragma unroll
        for (int mt = 0; mt < 8; ++mt) {
          bf16_t* hb = (mt < 4) ? h0 : h1;
          bf16x4 v;
          v[0] = (bf16_t)fmaxf(acc[nt][mt][0] + bv.x, 0.f);
          v[1] = (bf16_t)fmaxf(acc[nt][mt][1] + bv.y, 0.f);
          v[2] = (bf16_t)fmaxf(acc[nt][mt][2] + bv.z, 0.f);
          v[3] = (bf16_t)fmaxf(acc[nt][mt][3] + bv.w, 0.f);
          int off = (((mt & 3) * 8 + ks_) * 64 + qp * 16 + r) * 8 + e0;
          *(bf16x4*)&hb[off] = v;
        }
      }
    } else {
      // last layer: bias+relu fp32, sum over all 128 m-rows (i0 and i1
      // partials both belong to xg[b]), then PLAIN float4 store of this
      // block's partial row part[bx][n] -- no atomics.
      #pragma unroll
      for (int nt = 0; nt < 4; ++nt) {
        int k0 = wave * 64 + nt * 16 + q * 4;
        float4 bv = *(const float4*)&bias[k0];
        float p0 = 0.f, p1 = 0.f, p2 = 0.f, p3 = 0.f;
        #pragma unroll
        for (int mt = 0; mt < 8; ++mt) {
          p0 += fmaxf(acc[nt][mt][0] + bv.x, 0.f);
          p1 += fmaxf(acc[nt][mt][1] + bv.y, 0.f);
          p2 += fmaxf(acc[nt][mt][2] + bv.z, 0.f);
          p3 += fmaxf(acc[nt][mt][3] + bv.w, 0.f);
        }
        #pragma unroll
        for (int d = 1; d < 16; d <<= 1) {
          p0 += __shfl_xor(p0, d, 64);
          p1 += __shfl_xor(p1, d, 64);
          p2 += __shfl_xor(p2, d, 64);
          p3 += __shfl_xor(p3, d, 64);
        }
        if (r == 0) {
          float4 pv = make_float4(p0, p1, p2, p3);
          *(float4*)&part[(size_t)bx * 256 + k0] = pv;
        }
      }
    }
  }
}

// ---------------- partial reduce + f-MLP + log_softmax (tiny, fp32) --------
__global__ __launch_bounds__(256) void rn_f_kernel(
    const float* __restrict__ part,
    const float* __restrict__ f1w, const float* __restrict__ f1b,
    const float* __restrict__ f2w, const float* __restrict__ f2b,
    const float* __restrict__ f3w, const float* __restrict__ f3b,
    float* __restrict__ out)
{
  __shared__ float xs[256], t1[256], t2[256], lg[28], lse[1];
  int b = blockIdx.x, tid = threadIdx.x;
  // reduce the 32 per-ip partials of batch b (coalesced 1 KB/wave per iter)
  float s = 0.f;
  const float* pb = part + (size_t)b * 32 * 256;
  #pragma unroll 8
  for (int i = 0; i < 32; ++i) s += pb[i * 256 + tid];
  xs[tid] = s;
  __syncthreads();
  float acc = f1b[tid];
  for (int k = 0; k < 256; ++k) acc += xs[k] * f1w[k * 256 + tid];
  t1[tid] = fmaxf(acc, 0.f);
  __syncthreads();
  acc = f2b[tid];
  for (int k = 0; k < 256; ++k) acc += t1[k] * f2w[k * 256 + tid];
  t2[tid] = fmaxf(acc, 0.f);
  __syncthreads();
  if (tid < 28) {
    float a2 = f3b[tid];
    for (int k = 0; k < 256; ++k) a2 += t2[k] * f3w[k * 28 + tid];
    lg[tid] = a2;
  }
  __syncthreads();
  if (tid == 0) {
    float m = lg[0];
    for (int j = 1; j < 28; ++j) m = fmaxf(m, lg[j]);
    float se = 0.f;
    for (int j = 0; j < 28; ++j) se += expf(lg[j] - m);
    lse[0] = m + logf(se);
  }
  __syncthreads();
  if (tid < 28) out[b * 28 + tid] = lg[tid] - lse[0];
}

// ---------------------------------------------------------------------------
extern "C" void kernel_launch(void* const* d_in, const int* in_sizes, int n_in,
                              void* d_out, int out_size, void* d_ws, size_t ws_size,
                              hipStream_t stream) {
  (void)in_sizes; (void)n_in; (void)out_size; (void)ws_size;
  const float* x   = (const float*)d_in[0];
  const float* qst = (const float*)d_in[1];
  const float* g1w = (const float*)d_in[2];
  const float* g1b = (const float*)d_in[3];
  const float* g2w = (const float*)d_in[4];
  const float* g2b = (const float*)d_in[5];
  const float* g3w = (const float*)d_in[6];
  const float* g3b = (const float*)d_in[7];
  const float* g4w = (const float*)d_in[8];
  const float* g4b = (const float*)d_in[9];
  const float* f1w = (const float*)d_in[10];
  const float* f1b = (const float*)d_in[11];
  const float* f2w = (const float*)d_in[12];
  const float* f2b = (const float*)d_in[13];
  const float* f3w = (const float*)d_in[14];
  const float* f3b = (const float*)d_in[15];
  float* out = (float*)d_out;

  float*  A    = (float*)d_ws;
  float*  C    = A + 4096 * 256;
  bf16_t* Wt   = (bf16_t*)(C + 4096 * 256);
  float*  part = (float*)((char*)Wt + 3 * 65536 * sizeof(bf16_t));

  rn_prep_kernel<<<256 + 48, 256, 0, stream>>>(
      x, qst, g1w, g1b, g2w, g3w, g4w, A, C, Wt);
  rn_main_kernel<<<2048, 256, 0, stream>>>(A, C, Wt, g2b, g3b, g4b, part);
  rn_f_kernel<<<64, 256, 0, stream>>>(part, f1w, f1b, f2w, f2b, f3w, f3b, out);
}

// Round 9
// 248.529 us; speedup vs baseline: 1.0153x; 1.0113x over previous
//
#include <hip/hip_runtime.h>

typedef __bf16 bf16_t;
typedef __bf16 bf16x8 __attribute__((ext_vector_type(8)));
typedef __bf16 bf16x4 __attribute__((ext_vector_type(4)));
typedef float  f32x4  __attribute__((ext_vector_type(4)));
typedef float  f32x16 __attribute__((ext_vector_type(16)));

// ---------------------------------------------------------------------------
// Round 9: switch to v_mfma_f32_32x32x16_bf16.
// Evidence chain: r4 (2w lockstep, W global) = r5 (+pipeline) = r6 (4w indep)
// = r8 (1w, W register-stationary) = 139-148us @ MfmaUtil ~30, with HBM,
// LDS-conflict, TCP and spill all individually eliminated.  The only factor
// common to all: the 6.29M 16x16x32 MFMA instruction stream.  r8's serial
// timeline fits an effective ~32 SIMD-cyc per MFMA instruction (issue/pipe
// cadence), not the 19.4 FLOP-derived figure -> instruction-cadence-limited.
// 32x32x16 moves 2x the FLOPs per instruction at a HIGHER measured ceiling
// (2495 vs 2075 TF): halves the instruction stream.
//
// Workspace:
//   A    : [4096][256] f32                                         4 MB
//   C    : [4096][256] f32                                         4 MB
//   Wt   : 3 x [256][256] bf16 in 32x32x16 A-fragment layout:
//          idx = ((tile32*16 + ks16)*64 + hi*32 + r5)*8 + e
//          (tile32=no>>5, r5=no&31, ks16=k>>4, hi=(k>>3)&1, e=k&7)
//          per-(tile,ks) wave load = one 1 KB coalesced transaction. 384 KB
//   part : [2048][256] f32  per-block partial pair-sums            2 MB
//
// h in LDS: B-fragment-linear [mt32(4)][ks16(16)][lane(64)][e(8)] = 64 KB,
//   element (m,k): mt=m>>5, lane = ((k>>3)&1)*32 + (m&31), e=k&7.
// All LDS reads/writes lane-contiguous -> zero bank conflicts.
// ---------------------------------------------------------------------------

// ---------------- prep: A, C, weight fragment-relayout ----------------------
__global__ __launch_bounds__(256) void rn_prep_kernel(
    const float* __restrict__ x, const float* __restrict__ qst,
    const float* __restrict__ g1w, const float* __restrict__ g1b,
    const float* __restrict__ g2w, const float* __restrict__ g3w,
    const float* __restrict__ g4w,
    float* __restrict__ A, float* __restrict__ C,
    bf16_t* __restrict__ Wt)
{
  __shared__ float T[64][65];   // transpose tile (only used by that branch)
  int blk = blockIdx.x;
  int n   = threadIdx.x;  // 0..255
  if (blk < 256) {
    // block = (b, jg): rows jg*16 .. jg*16+15 of batch b; thread = output col n
    int b  = blk >> 2;
    int jg = (blk & 3) * 16;
    float accQ = g1b[n];
    const float* qb = qst + b * 128;
    #pragma unroll 8
    for (int qi = 0; qi < 128; ++qi)
      accQ += qb[qi] * g1w[(52 + qi) * 256 + n];

    float w24 = g1w[24 * 256 + n], w25 = g1w[25 * 256 + n];
    float w50 = g1w[50 * 256 + n], w51 = g1w[51 * 256 + n];
    float accA[16], accC[16];
    #pragma unroll
    for (int t = 0; t < 16; ++t) {
      int j = jg + t;
      // faithful to (a/d - d/2)/(d/2.0) float arithmetic, d=8 (exact pow2 ops)
      float cx = ((float)j * 0.125f - 4.0f) * 0.25f;
      float cy = ((float)(j & 7) - 4.0f) * 0.25f;
      accA[t] = cx * w24 + cy * w25;
      accC[t] = accQ + cx * w50 + cy * w51;
    }
    for (int c = 0; c < 24; ++c) {
      float wa = g1w[c * 256 + n];
      float wc = g1w[(26 + c) * 256 + n];
      const float* xc = x + (b * 24 + c) * 64 + jg;
      #pragma unroll
      for (int t = 0; t < 16; ++t) {
        float xv = xc[t];   // uniform per thread -> scalar load
        accA[t] += xv * wa;
        accC[t] += xv * wc;
      }
    }
    #pragma unroll
    for (int t = 0; t < 16; ++t) {
      A[(b * 64 + jg + t) * 256 + n] = accA[t];
      C[(b * 64 + jg + t) * 256 + n] = accC[t];
    }
  } else {
    // LDS-tiled transpose: g2/g3/g4 [in(k)][out(no)] f32 -> bf16 32x32x16
    // A-fragment layout.
    int t   = blk - 256;
    int mat = t >> 4;                 // 0..2
    int tl  = t & 15;                 // 4x4 tiles of 64x64
    int kt  = (tl & 3) * 64;
    int nt_ = (tl >> 2) * 64;
    const float* W = (mat == 0) ? g2w : (mat == 1 ? g3w : g4w);
    int lane = n & 63, w = n >> 6;
    #pragma unroll
    for (int it = 0; it < 16; ++it) {
      int kl = w * 16 + it;
      T[kl][lane] = W[(kt + kl) * 256 + nt_ + lane];   // coalesced 256B/wave
    }
    __syncthreads();
    #pragma unroll
    for (int it = 0; it < 16; ++it) {
      int nl  = w * 16 + it;
      int no  = nt_ + nl;     // output-neuron index
      int k   = kt + lane;    // input index
      int tile = no >> 5, r5 = no & 31;
      int ksI  = k >> 4, hi = (k >> 3) & 1, e = k & 7;
      int idx  = ((tile * 16 + ksI) * 64 + hi * 32 + r5) * 8 + e;
      Wt[mat * 65536 + idx] = (bf16_t)T[lane][nl];
    }
  }
}

// ---------------- main fused g-MLP (layers 2..4) + pair partial-sum --------
// one block per (b, i-pair): M = 128 rows (2 i x 64 j), N = K = 256, 4 waves.
// Wave w owns n-rows [w*64, w*64+64) (nt=0..1, 32 each) and ALL 128 m-rows
// (mt=0..3, 32 each).  Per ks16 (16 steps): 2 wf global (1 KB coalesced,
// L2-resident) + 4 hf LDS (lane-contiguous) -> 8 MFMA 32x32x16.
// acc = 2x4 f32x16 = 128 AGPR; total ~185 regs -> 2 waves/SIMD, 2 blocks/CU.
__global__ __launch_bounds__(256, 2) void rn_main_kernel(
    const float* __restrict__ A, const float* __restrict__ C,
    const bf16_t* __restrict__ Wt,
    const float* __restrict__ g2b, const float* __restrict__ g3b,
    const float* __restrict__ g4b,
    float* __restrict__ part)
{
  __shared__ bf16_t h[32768];   // 64 KB: [mt(4)][ks(16)][lane(64)][e(8)]

  int tid  = threadIdx.x;
  int bx0  = blockIdx.x;
  // bijective XCD swizzle (2048 % 8 == 0)
  int bx   = (bx0 & 7) * 256 + (bx0 >> 3);
  int b    = bx >> 5;          // batch
  int ip   = bx & 31;          // i-pair: i = 2*ip, 2*ip+1
  int lane = tid & 63;
  int wave = tid >> 6;
  int c5   = lane & 31;        // 32-dim index within MFMA tile
  int hi5  = lane >> 5;        // k-half selector

  // ---- build h into fragment-linear layout ----
  // wave w builds mt=w: m = w*32+c5 -> ii = w>>1, j = (w&1)*32+c5.
  // thread covers k = it*16 + hi5*8 + (0..7).  Writes lane-contiguous b128.
  {
    const float* Ar = A + ((size_t)b * 64 + ((wave & 1) * 32 + c5)) * 256;
    const float* Cr = C + ((size_t)b * 64 + ip * 2 + (wave >> 1)) * 256;
    #pragma unroll
    for (int it = 0; it < 16; ++it) {
      int k0 = it * 16 + hi5 * 8;
      const float4 a0 = *(const float4*)(Ar + k0);
      const float4 a1 = *(const float4*)(Ar + k0 + 4);
      const float4 c0 = *(const float4*)(Cr + k0);
      const float4 c1 = *(const float4*)(Cr + k0 + 4);
      bf16x8 v;
      v[0] = (bf16_t)fmaxf(a0.x + c0.x, 0.f);
      v[1] = (bf16_t)fmaxf(a0.y + c0.y, 0.f);
      v[2] = (bf16_t)fmaxf(a0.z + c0.z, 0.f);
      v[3] = (bf16_t)fmaxf(a0.w + c0.w, 0.f);
      v[4] = (bf16_t)fmaxf(a1.x + c1.x, 0.f);
      v[5] = (bf16_t)fmaxf(a1.y + c1.y, 0.f);
      v[6] = (bf16_t)fmaxf(a1.z + c1.z, 0.f);
      v[7] = (bf16_t)fmaxf(a1.w + c1.w, 0.f);
      *(bf16x8*)&h[((wave * 16 + it) * 64 + lane) * 8] = v;
    }
  }

  for (int L = 0; L < 3; ++L) {
    __syncthreads();           // h (build or previous epilogue) visible
    const bf16_t* Wl   = Wt + L * 65536;
    const float*  bias = (L == 0) ? g2b : (L == 1) ? g3b : g4b;

    f32x16 acc[2][4];          // [nt][mt]
    #pragma unroll
    for (int nt = 0; nt < 2; ++nt)
      #pragma unroll
      for (int mt = 0; mt < 4; ++mt)
        #pragma unroll
        for (int e = 0; e < 16; ++e) acc[nt][mt][e] = 0.f;

    #pragma unroll
    for (int ks = 0; ks < 16; ++ks) {
      bf16x8 wf[2], hf[4];
      #pragma unroll
      for (int nt = 0; nt < 2; ++nt) {
        int tile = wave * 2 + nt;
        wf[nt] = *(const bf16x8*)&Wl[((tile * 16 + ks) * 64 + lane) * 8];
      }
      #pragma unroll
      for (int mt = 0; mt < 4; ++mt)
        hf[mt] = *(const bf16x8*)&h[((mt * 16 + ks) * 64 + lane) * 8];
      __builtin_amdgcn_s_setprio(1);
      #pragma unroll
      for (int nt = 0; nt < 2; ++nt)
        #pragma unroll
        for (int mt = 0; mt < 4; ++mt)
          acc[nt][mt] = __builtin_amdgcn_mfma_f32_32x32x16_bf16(
              wf[nt], hf[mt], acc[nt][mt], 0, 0, 0);
      __builtin_amdgcn_s_setprio(0);
    }

    __syncthreads();           // all reads of h done -> safe to overwrite

    if (L < 2) {
      // D reg v of tile (nt,mt): m = mt*32 + c5,
      // n = wave*64 + nt*32 + (v&3) + 4*hi5 + 8*((v>>2)&1) + 16*(v>>4...)
      // packed per a=v>>2: n = nb + j (j=v&3), nb = wave*64+nt*32+4*hi5
      //                                            +8*(a&1)+16*(a>>1).
      // Next-layer h slot for (m, k=n): ks' = n>>4 = wave*4+nt*2+(a>>1),
      // lane' = (a&1)*32... wait hi'' = (n>>3)&1 = a&1; e0 = 4*hi5.
      #pragma unroll
      for (int nt = 0; nt < 2; ++nt) {
        #pragma unroll
        for (int a = 0; a < 4; ++a) {
          int nb = wave * 64 + nt * 32 + 4 * hi5 + 8 * (a & 1) + 16 * (a >> 1);
          float4 bv = *(const float4*)&bias[nb];
          int ksp = wave * 4 + nt * 2 + (a >> 1);
          #pragma unroll
          for (int mt = 0; mt < 4; ++mt) {
            bf16x4 v;
            v[0] = (bf16_t)fmaxf(acc[nt][mt][a * 4 + 0] + bv.x, 0.f);
            v[1] = (bf16_t)fmaxf(acc[nt][mt][a * 4 + 1] + bv.y, 0.f);
            v[2] = (bf16_t)fmaxf(acc[nt][mt][a * 4 + 2] + bv.z, 0.f);
            v[3] = (bf16_t)fmaxf(acc[nt][mt][a * 4 + 3] + bv.w, 0.f);
            int off = ((mt * 16 + ksp) * 64 + (a & 1) * 32 + c5) * 8 + 4 * hi5;
            *(bf16x4*)&h[off] = v;
          }
        }
      }
    } else {
      // last layer: bias+relu fp32, sum over all 128 m-rows (mt in-register,
      // then the 32 c5-lanes), PLAIN float4 store of the block partial.
      #pragma unroll
      for (int nt = 0; nt < 2; ++nt) {
        #pragma unroll
        for (int a = 0; a < 4; ++a) {
          int nb = wave * 64 + nt * 32 + 4 * hi5 + 8 * (a & 1) + 16 * (a >> 1);
          float4 bv = *(const float4*)&bias[nb];
          float p0 = 0.f, p1 = 0.f, p2 = 0.f, p3 = 0.f;
          #pragma unroll
          for (int mt = 0; mt < 4; ++mt) {
            p0 += fmaxf(acc[nt][mt][a * 4 + 0] + bv.x, 0.f);
            p1 += fmaxf(acc[nt][mt][a * 4 + 1] + bv.y, 0.f);
            p2 += fmaxf(acc[nt][mt][a * 4 + 2] + bv.z, 0.f);
            p3 += fmaxf(acc[nt][mt][a * 4 + 3] + bv.w, 0.f);
          }
          #pragma unroll
          for (int d = 1; d < 32; d <<= 1) {
            p0 += __shfl_xor(p0, d, 64);
            p1 += __shfl_xor(p1, d, 64);
            p2 += __shfl_xor(p2, d, 64);
            p3 += __shfl_xor(p3, d, 64);
          }
          if (c5 == 0) {
            float4 pv = make_float4(p0, p1, p2, p3);
            *(float4*)&part[(size_t)bx * 256 + nb] = pv;
          }
        }
      }
    }
  }
}

// ---------------- partial reduce + f-MLP + log_softmax (tiny, fp32) --------
__global__ __launch_bounds__(256) void rn_f_kernel(
    const float* __restrict__ part,
    const float* __restrict__ f1w, const float* __restrict__ f1b,
    const float* __restrict__ f2w, const float* __restrict__ f2b,
    const float* __restrict__ f3w, const float* __restrict__ f3b,
    float* __restrict__ out)
{
  __shared__ float xs[256], t1[256], t2[256], lg[28], lse[1];
  int b = blockIdx.x, tid = threadIdx.x;
  // reduce the 32 per-ip partials of batch b (coalesced 1 KB/wave per iter)
  float s = 0.f;
  const float* pb = part + (size_t)b * 32 * 256;
  #pragma unroll 8
  for (int i = 0; i < 32; ++i) s += pb[i * 256 + tid];
  xs[tid] = s;
  __syncthreads();
  float acc = f1b[tid];
  for (int k = 0; k < 256; ++k) acc += xs[k] * f1w[k * 256 + tid];
  t1[tid] = fmaxf(acc, 0.f);
  __syncthreads();
  acc = f2b[tid];
  for (int k = 0; k < 256; ++k) acc += t1[k] * f2w[k * 256 + tid];
  t2[tid] = fmaxf(acc, 0.f);
  __syncthreads();
  if (tid < 28) {
    float a2 = f3b[tid];
    for (int k = 0; k < 256; ++k) a2 += t2[k] * f3w[k * 28 + tid];
    lg[tid] = a2;
  }
  __syncthreads();
  if (tid == 0) {
    float m = lg[0];
    for (int j = 1; j < 28; ++j) m = fmaxf(m, lg[j]);
    float se = 0.f;
    for (int j = 0; j < 28; ++j) se += expf(lg[j] - m);
    lse[0] = m + logf(se);
  }
  __syncthreads();
  if (tid < 28) out[b * 28 + tid] = lg[tid] - lse[0];
}

// ---------------------------------------------------------------------------
extern "C" void kernel_launch(void* const* d_in, const int* in_sizes, int n_in,
                              void* d_out, int out_size, void* d_ws, size_t ws_size,
                              hipStream_t stream) {
  (void)in_sizes; (void)n_in; (void)out_size; (void)ws_size;
  const float* x   = (const float*)d_in[0];
  const float* qst = (const float*)d_in[1];
  const float* g1w = (const float*)d_in[2];
  const float* g1b = (const float*)d_in[3];
  const float* g2w = (const float*)d_in[4];
  const float* g2b = (const float*)d_in[5];
  const float* g3w = (const float*)d_in[6];
  const float* g3b = (const float*)d_in[7];
  const float* g4w = (const float*)d_in[8];
  const float* g4b = (const float*)d_in[9];
  const float* f1w = (const float*)d_in[10];
  const float* f1b = (const float*)d_in[11];
  const float* f2w = (const float*)d_in[12];
  const float* f2b = (const float*)d_in[13];
  const float* f3w = (const float*)d_in[14];
  const float* f3b = (const float*)d_in[15];
  float* out = (float*)d_out;

  float*  A    = (float*)d_ws;
  float*  C    = A + 4096 * 256;
  bf16_t* Wt   = (bf16_t*)(C + 4096 * 256);
  float*  part = (float*)((char*)Wt + 3 * 65536 * sizeof(bf16_t));

  rn_prep_kernel<<<256 + 48, 256, 0, stream>>>(
      x, qst, g1w, g1b, g2w, g3w, g4w, A, C, Wt);
  rn_main_kernel<<<2048, 256, 0, stream>>>(A, C, Wt, g2b, g3b, g4b, part);
  rn_f_kernel<<<64, 256, 0, stream>>>(part, f1w, f1b, f2w, f2b, f3w, f3b, out);
}

// Round 10
// 234.509 us; speedup vs baseline: 1.0760x; 1.0598x over previous
//
#include <hip/hip_runtime.h>

typedef __bf16 bf16_t;
typedef __bf16 bf16x8 __attribute__((ext_vector_type(8)));
typedef __bf16 bf16x4 __attribute__((ext_vector_type(4)));
typedef float  f32x4  __attribute__((ext_vector_type(4)));

// ---------------------------------------------------------------------------
// Workspace layout (floats unless noted):
//   Ap : [64][16384] f32  xf@W1[0:26] in h-FRAGMENT-LINEAR order:
//        Ap[b*16384 + ((jt*8+it)*64 + q*16 + r)*8 + e] = A[b][jt*16+r][it*32+q*8+e]
//        -> main-kernel build reads are lane-contiguous (no gather).   4 MB
//   C  : [4096][256] f32  (xf @ W1[26:52] + qst @ W1[52:180] + b1)     4 MB
//   Wt : 3 x [256][256] bf16 in MFMA A-fragment layout:
//        [mat][tile16(no>>4)][ks(k>>5)][lane(q*16+r)][e]; per-(tile,ks)
//        wave load is one coalesced 1 KB transaction.                  384 KB
//   xg : [64][256] f32  (pair-summed g output, atomically accumulated) 64 KB
//
// h in LDS: B-fragment-linear  h[chunk = mt*8+ks][lane = q*16+r][e]
//   <-> h[m = mt*16+r][k = ks*32+q*8+e]  -> all LDS ops lane-contiguous,
//   zero bank conflicts by construction.
//
// Round 10 = r4 (best measured: 138.9us main) + ONE change: A stored in
// fragment-linear order so the build phase loads are coalesced.  r4-r9
// established: MFMA-pipe busy is pinned at ~43us (the true work) with duty
// ~30% across {2w lockstep, SW-pipeline, 4w independent, 1w register-W,
// 32x32 MFMA} -> the stall is not bank conflicts, not W-path, not occupancy,
// not MFMA cadence.  The one untouched invariant: the build's 64-lines-per-
// instruction A-gather (lane stride 1KB) hitting the TCP request path.
// ---------------------------------------------------------------------------

// ---------------- prep: Ap, C, weight fragment-relayout, zero xg ------------
__global__ __launch_bounds__(256) void rn_prep_kernel(
    const float* __restrict__ x, const float* __restrict__ qst,
    const float* __restrict__ g1w, const float* __restrict__ g1b,
    const float* __restrict__ g2w, const float* __restrict__ g3w,
    const float* __restrict__ g4w,
    float* __restrict__ Ap, float* __restrict__ C,
    bf16_t* __restrict__ Wt, float* __restrict__ xg)
{
  __shared__ float T[64][65];   // transpose tile (only used by that branch)
  int blk = blockIdx.x;
  int n   = threadIdx.x;  // 0..255
  if (blk < 256) {
    // block = (b, jg): rows jg*16 .. jg*16+15 of batch b; thread = output col n
    int b  = blk >> 2;
    int jg = (blk & 3) * 16;
    float accQ = g1b[n];
    const float* qb = qst + b * 128;
    #pragma unroll 8
    for (int qi = 0; qi < 128; ++qi)
      accQ += qb[qi] * g1w[(52 + qi) * 256 + n];

    float w24 = g1w[24 * 256 + n], w25 = g1w[25 * 256 + n];
    float w50 = g1w[50 * 256 + n], w51 = g1w[51 * 256 + n];
    float accA[16], accC[16];
    #pragma unroll
    for (int t = 0; t < 16; ++t) {
      int j = jg + t;
      // faithful to (a/d - d/2)/(d/2.0) float arithmetic, d=8 (exact pow2 ops)
      float cx = ((float)j * 0.125f - 4.0f) * 0.25f;
      float cy = ((float)(j & 7) - 4.0f) * 0.25f;
      accA[t] = cx * w24 + cy * w25;
      accC[t] = accQ + cx * w50 + cy * w51;
    }
    for (int c = 0; c < 24; ++c) {
      float wa = g1w[c * 256 + n];
      float wc = g1w[(26 + c) * 256 + n];
      const float* xc = x + (b * 24 + c) * 64 + jg;
      #pragma unroll
      for (int t = 0; t < 16; ++t) {
        float xv = xc[t];   // uniform per thread -> scalar load
        accA[t] += xv * wa;
        accC[t] += xv * wc;
      }
    }
    // A in fragment-linear order: j = jt*16 + t (jt = blk&3, r = t), k = n.
    int jt = blk & 3;
    int itA = n >> 5, qA = (n >> 3) & 3, eA = n & 7;
    int baseA = b * 16384 + (jt * 8 + itA) * 512 + qA * 128 + eA;
    #pragma unroll
    for (int t = 0; t < 16; ++t) {
      Ap[baseA + t * 8] = accA[t];
      C[(b * 64 + jg + t) * 256 + n] = accC[t];
    }
  } else if (blk < 256 + 48) {
    // LDS-tiled transpose: g2/g3/g4 [in(k)][out(no)] f32 -> bf16 fragment
    // layout: element (no,k) -> [(no>>4)*8 + (k>>5)][((k>>3)&3)*16 + (no&15)][k&7]
    int t   = blk - 256;
    int mat = t >> 4;                 // 0..2
    int tl  = t & 15;                 // 4x4 tiles of 64x64
    int kt  = (tl & 3) * 64;
    int nt_ = (tl >> 2) * 64;
    const float* W = (mat == 0) ? g2w : (mat == 1 ? g3w : g4w);
    int lane = n & 63, w = n >> 6;
    #pragma unroll
    for (int it = 0; it < 16; ++it) {
      int kl = w * 16 + it;
      T[kl][lane] = W[(kt + kl) * 256 + nt_ + lane];   // coalesced 256B/wave
    }
    __syncthreads();
    #pragma unroll
    for (int it = 0; it < 16; ++it) {
      int nl  = w * 16 + it;
      int no  = nt_ + nl;     // output-neuron index
      int k   = kt + lane;    // input index
      int tile = no >> 4, rr = no & 15;
      int ksI  = k >> 5,  qI = (k >> 3) & 3, e = k & 7;
      int idx  = ((tile * 8 + ksI) * 64 + qI * 16 + rr) * 8 + e;
      Wt[mat * 65536 + idx] = (bf16_t)T[lane][nl];
    }
  } else {
    int idx = (blk - (256 + 48)) * 256 + n;  // 64 blocks -> 16384
    xg[idx] = 0.f;
  }
}

// ---------------- main fused g-MLP (layers 2..4) + pair sum ----------------
// one block per (b, i-pair): M = 128 rows (2 i x 64 j), N = K = 256, 4 waves.
// Wave owns n-rows [wave*64, wave*64+64) (nt=0..3) and ALL 128 m-rows
// (mt=0..7: h0 for mt<4, h1 for mt>=4).
// Per ks: 4 wf global (1 KB contiguous each, L1-shared across blocks)
//       + 8 hf LDS (lane-contiguous, conflict-free) -> 32 MFMA.
// acc[4][8] = 128 AGPR + ~100 arch VGPR -> fits 256 budget at 2 blocks/CU.
__global__ __launch_bounds__(256, 2) void rn_main_kernel(
    const float* __restrict__ Ap, const float* __restrict__ C,
    const bf16_t* __restrict__ Wt,
    const float* __restrict__ g2b, const float* __restrict__ g3b,
    const float* __restrict__ g4b,
    float* __restrict__ xg)
{
  __shared__ bf16_t h0[16384];   // 32 KB: [chunk=mt*8+ks][lane][8]
  __shared__ bf16_t h1[16384];   // 32 KB

  int tid  = threadIdx.x;
  int bx0  = blockIdx.x;
  // bijective XCD swizzle (2048 % 8 == 0): 256 consecutive work-units per
  // XCD -> the 32 blocks sharing a batch b stay on one XCD's L2
  int bx   = (bx0 & 7) * 256 + (bx0 >> 3);
  int b    = bx >> 5;          // batch
  int ip   = bx & 31;          // i-pair: i = 2*ip, 2*ip+1
  int lane = tid & 63;
  int wave = tid >> 6;
  int r    = lane & 15;        // 16-dim index within MFMA tile
  int q    = lane >> 4;        // quad: k-run selector / D-row group

  // ---- build h rows into fragment-linear layout ----
  // wave w builds chunks (mt=w, ks=it): thread (q,r) -> m-row j = w*16+r,
  // k-run = it*32+q*8.  A is pre-arranged so this read is lane-contiguous:
  // Ap slot for (jt=wave, it, lane, e) = wave*4096 + it*512 + lane*8 + e.
  // C reads are 2-4 line broadcasts (cheap).  LDS writes lane-contiguous.
  {
    const float* Apb = Ap + (size_t)b * 16384 + wave * 4096;
    const float* Cr  = C + ((size_t)b * 64 + ip * 2) * 256;
    #pragma unroll
    for (int it = 0; it < 8; ++it) {
      int k0 = it * 32 + q * 8;
      const float4 a0  = *(const float4*)(Apb + it * 512 + lane * 8);
      const float4 a1  = *(const float4*)(Apb + it * 512 + lane * 8 + 4);
      const float4 c00 = *(const float4*)(Cr + k0);
      const float4 c01 = *(const float4*)(Cr + k0 + 4);
      const float4 c10 = *(const float4*)(Cr + 256 + k0);
      const float4 c11 = *(const float4*)(Cr + 256 + k0 + 4);
      bf16x8 v0, v1;
      v0[0] = (bf16_t)fmaxf(a0.x + c00.x, 0.f);
      v0[1] = (bf16_t)fmaxf(a0.y + c00.y, 0.f);
      v0[2] = (bf16_t)fmaxf(a0.z + c00.z, 0.f);
      v0[3] = (bf16_t)fmaxf(a0.w + c00.w, 0.f);
      v0[4] = (bf16_t)fmaxf(a1.x + c01.x, 0.f);
      v0[5] = (bf16_t)fmaxf(a1.y + c01.y, 0.f);
      v0[6] = (bf16_t)fmaxf(a1.z + c01.z, 0.f);
      v0[7] = (bf16_t)fmaxf(a1.w + c01.w, 0.f);
      v1[0] = (bf16_t)fmaxf(a0.x + c10.x, 0.f);
      v1[1] = (bf16_t)fmaxf(a0.y + c10.y, 0.f);
      v1[2] = (bf16_t)fmaxf(a0.z + c10.z, 0.f);
      v1[3] = (bf16_t)fmaxf(a0.w + c10.w, 0.f);
      v1[4] = (bf16_t)fmaxf(a1.x + c11.x, 0.f);
      v1[5] = (bf16_t)fmaxf(a1.y + c11.y, 0.f);
      v1[6] = (bf16_t)fmaxf(a1.z + c11.z, 0.f);
      v1[7] = (bf16_t)fmaxf(a1.w + c11.w, 0.f);
      int off = ((wave * 8 + it) * 64 + lane) * 8;
      *(bf16x8*)&h0[off] = v0;
      *(bf16x8*)&h1[off] = v1;
    }
  }

  for (int L = 0; L < 3; ++L) {
    __syncthreads();           // h (build or previous epilogue) visible
    // this wave's 4 W tiles: tile = wave*4 + nt  -> base offset wave*16384
    const bf16_t* Wl   = Wt + L * 65536 + wave * 16384;
    const float*  bias = (L == 0) ? g2b : (L == 1) ? g3b : g4b;

    f32x4 acc[4][8];           // [nt][mt]
    #pragma unroll
    for (int nt = 0; nt < 4; ++nt)
      #pragma unroll
      for (int mt = 0; mt < 8; ++mt)
        #pragma unroll
        for (int e = 0; e < 4; ++e) acc[nt][mt][e] = 0.f;

    #pragma unroll
    for (int ks = 0; ks < 8; ++ks) {
      bf16x8 wf[4], hf[8];
      #pragma unroll
      for (int nt = 0; nt < 4; ++nt)
        wf[nt] = *(const bf16x8*)&Wl[((nt * 8 + ks) * 64 + lane) * 8];
      #pragma unroll
      for (int mt = 0; mt < 8; ++mt) {
        const bf16_t* hb = (mt < 4) ? h0 : h1;
        hf[mt] = *(const bf16x8*)&hb[(((mt & 3) * 8 + ks) * 64 + lane) * 8];
      }
      #pragma unroll
      for (int nt = 0; nt < 4; ++nt)
        #pragma unroll
        for (int mt = 0; mt < 8; ++mt)
          acc[nt][mt] = __builtin_amdgcn_mfma_f32_16x16x32_bf16(
              wf[nt], hf[mt], acc[nt][mt], 0, 0, 0);
    }

    __syncthreads();           // all reads of h done -> safe to overwrite

    if (L < 2) {
      // D value (nt,mt,e): n = wave*64+nt*16+q*4+e (next layer's k),
      // m = mt*16+r (mt<4 -> h0, else h1).  Fragment-linear write-back.
      #pragma unroll
      for (int nt = 0; nt < 4; ++nt) {
        int k0  = wave * 64 + nt * 16 + q * 4;
        float4 bv = *(const float4*)&bias[k0];
        int ks_ = k0 >> 5, rem = k0 & 31;
        int qp  = rem >> 3, e0 = rem & 7;     // e0 in {0,4}
        #pragma unroll
        for (int mt = 0; mt < 8; ++mt) {
          bf16_t* hb = (mt < 4) ? h0 : h1;
          bf16x4 v;
          v[0] = (bf16_t)fmaxf(acc[nt][mt][0] + bv.x, 0.f);
          v[1] = (bf16_t)fmaxf(acc[nt][mt][1] + bv.y, 0.f);
          v[2] = (bf16_t)fmaxf(acc[nt][mt][2] + bv.z, 0.f);
          v[3] = (bf16_t)fmaxf(acc[nt][mt][3] + bv.w, 0.f);
          int off = (((mt & 3) * 8 + ks_) * 64 + qp * 16 + r) * 8 + e0;
          *(bf16x4*)&hb[off] = v;
        }
      }
    } else {
      // last layer: bias+relu fp32, sum over all 128 m-rows
      // (mt in-register, then the 16 r-lanes), atomic to xg.
      #pragma unroll
      for (int nt = 0; nt < 4; ++nt) {
        int k0 = wave * 64 + nt * 16 + q * 4;
        float4 bv = *(const float4*)&bias[k0];
        float p0 = 0.f, p1 = 0.f, p2 = 0.f, p3 = 0.f;
        #pragma unroll
        for (int mt = 0; mt < 8; ++mt) {
          p0 += fmaxf(acc[nt][mt][0] + bv.x, 0.f);
          p1 += fmaxf(acc[nt][mt][1] + bv.y, 0.f);
          p2 += fmaxf(acc[nt][mt][2] + bv.z, 0.f);
          p3 += fmaxf(acc[nt][mt][3] + bv.w, 0.f);
        }
        #pragma unroll
        for (int d = 1; d < 16; d <<= 1) {
          p0 += __shfl_xor(p0, d, 64);
          p1 += __shfl_xor(p1, d, 64);
          p2 += __shfl_xor(p2, d, 64);
          p3 += __shfl_xor(p3, d, 64);
        }
        if (r == 0) {
          int nn = b * 256 + k0;
          atomicAdd(&xg[nn + 0], p0);
          atomicAdd(&xg[nn + 1], p1);
          atomicAdd(&xg[nn + 2], p2);
          atomicAdd(&xg[nn + 3], p3);
        }
      }
    }
  }
}

// ---------------- f-MLP + log_softmax (tiny, fp32) ----------------
__global__ __launch_bounds__(256) void rn_f_kernel(
    const float* __restrict__ xg,
    const float* __restrict__ f1w, const float* __restrict__ f1b,
    const float* __restrict__ f2w, const float* __restrict__ f2b,
    const float* __restrict__ f3w, const float* __restrict__ f3b,
    float* __restrict__ out)
{
  __shared__ float xs[256], t1[256], t2[256], lg[28], lse[1];
  int b = blockIdx.x, tid = threadIdx.x;
  xs[tid] = xg[b * 256 + tid];
  __syncthreads();
  float acc = f1b[tid];
  for (int k = 0; k < 256; ++k) acc += xs[k] * f1w[k * 256 + tid];
  t1[tid] = fmaxf(acc, 0.f);
  __syncthreads();
  acc = f2b[tid];
  for (int k = 0; k < 256; ++k) acc += t1[k] * f2w[k * 256 + tid];
  t2[tid] = fmaxf(acc, 0.f);
  __syncthreads();
  if (tid < 28) {
    float a2 = f3b[tid];
    for (int k = 0; k < 256; ++k) a2 += t2[k] * f3w[k * 28 + tid];
    lg[tid] = a2;
  }
  __syncthreads();
  if (tid == 0) {
    float m = lg[0];
    for (int j = 1; j < 28; ++j) m = fmaxf(m, lg[j]);
    float se = 0.f;
    for (int j = 0; j < 28; ++j) se += expf(lg[j] - m);
    lse[0] = m + logf(se);
  }
  __syncthreads();
  if (tid < 28) out[b * 28 + tid] = lg[tid] - lse[0];
}

// ---------------------------------------------------------------------------
extern "C" void kernel_launch(void* const* d_in, const int* in_sizes, int n_in,
                              void* d_out, int out_size, void* d_ws, size_t ws_size,
                              hipStream_t stream) {
  (void)in_sizes; (void)n_in; (void)out_size; (void)ws_size;
  const float* x   = (const float*)d_in[0];
  const float* qst = (const float*)d_in[1];
  const float* g1w = (const float*)d_in[2];
  const float* g1b = (const float*)d_in[3];
  const float* g2w = (const float*)d_in[4];
  const float* g2b = (const float*)d_in[5];
  const float* g3w = (const float*)d_in[6];
  const float* g3b = (const float*)d_in[7];
  const float* g4w = (const float*)d_in[8];
  const float* g4b = (const float*)d_in[9];
  const float* f1w = (const float*)d_in[10];
  const float* f1b = (const float*)d_in[11];
  const float* f2w = (const float*)d_in[12];
  const float* f2b = (const float*)d_in[13];
  const float* f3w = (const float*)d_in[14];
  const float* f3b = (const float*)d_in[15];
  float* out = (float*)d_out;

  float*  Ap = (float*)d_ws;
  float*  C  = Ap + 4096 * 256;
  bf16_t* Wt = (bf16_t*)(C + 4096 * 256);
  float*  xg = (float*)((char*)Wt + 3 * 65536 * sizeof(bf16_t));

  rn_prep_kernel<<<256 + 48 + 64, 256, 0, stream>>>(
      x, qst, g1w, g1b, g2w, g3w, g4w, Ap, C, Wt, xg);
  rn_main_kernel<<<2048, 256, 0, stream>>>(Ap, C, Wt, g2b, g3b, g4b, xg);
  rn_f_kernel<<<64, 256, 0, stream>>>(xg, f1w, f1b, f2w, f2b, f3w, f3b, out);
}

// Round 12
// 229.384 us; speedup vs baseline: 1.1000x; 1.0223x over previous
//
#include <hip/hip_runtime.h>

typedef __bf16 bf16_t;
typedef __bf16 bf16x8 __attribute__((ext_vector_type(8)));
typedef __bf16 bf16x4 __attribute__((ext_vector_type(4)));
typedef float  f32x4  __attribute__((ext_vector_type(4)));

// ---------------------------------------------------------------------------
// Workspace layout (floats unless noted):
//   Ap : [64][16384] f32  xf@W1[0:26] in h-FRAGMENT-LINEAR order:
//        slot ((jt*8+it)*64 + q*16 + r)*8 + e = A[b][jt*16+r][it*32+q*8+e]
//        -> build reads are lane-contiguous (r10: worth ~2us).        4 MB
//   C  : [4096][256] f32  (xf @ W1[26:52] + qst @ W1[52:180] + b1)    4 MB
//   Wt : 3 x [256][256] bf16 in MFMA A-fragment layout:
//        [mat][tile16(no>>4)][ks(k>>5)][lane(q*16+r)][e]; per-(tile,ks)
//        wave load is one coalesced 1 KB transaction.                 384 KB
//   part : [4096][256] f32  per-block partial pair-sums               4 MB
//
// h in LDS: B-fragment-linear  h[chunk = mt*8+ks][lane = q*16+r][e]
//   <-> h[m = mt*16+r][k = ks*32+q*8+e]  -> all LDS ops lane-contiguous,
//   zero bank conflicts by construction.
//
// Round 12 (= round 11 resubmit; r11 was an infra failure, no data):
// BARRIER-SKELETON change (the one structure never varied in r0-r10, all
// of which pinned MfmaUtil*dur ~= 44us at ~30% duty).
// Ping-pong h buffers: layer L reads hA and writes hB (disjoint) -> the
// mid-layer barrier (read/write WAW on one buffer) is eliminated; only one
// barrier per layer boundary remains.  Barriers per block: 6 -> 3, and
// between barriers waves skew across {build | MFMA | epilogue} phases,
// covering each other's stalls (this is the m97->T3 mechanism: the
// vmcnt(0)+lgkmcnt(0) drain at each s_barrier is the documented ~37%-duty
// ceiling of the 2-barrier structure).  Geometry = r6 (M=64, 2 blocks/CU,
// partial stores, grid 4096) + r10's coalesced Ap build + T5 setprio.
// Race audit: build->hA |bar| L0 rd hA wr hB |bar| L1 rd hB wr hA |bar|
// L2 rd hA -> every read-set/write-set pair between consecutive barriers
// is disjoint; all barriers block-uniform.
// ---------------------------------------------------------------------------

// ---------------- prep: Ap, C, weight fragment-relayout ---------------------
__global__ __launch_bounds__(256) void rn_prep_kernel(
    const float* __restrict__ x, const float* __restrict__ qst,
    const float* __restrict__ g1w, const float* __restrict__ g1b,
    const float* __restrict__ g2w, const float* __restrict__ g3w,
    const float* __restrict__ g4w,
    float* __restrict__ Ap, float* __restrict__ C,
    bf16_t* __restrict__ Wt)
{
  __shared__ float T[64][65];   // transpose tile (only used by that branch)
  int blk = blockIdx.x;
  int n   = threadIdx.x;  // 0..255
  if (blk < 256) {
    // block = (b, jg): rows jg*16 .. jg*16+15 of batch b; thread = output col n
    int b  = blk >> 2;
    int jg = (blk & 3) * 16;
    float accQ = g1b[n];
    const float* qb = qst + b * 128;
    #pragma unroll 8
    for (int qi = 0; qi < 128; ++qi)
      accQ += qb[qi] * g1w[(52 + qi) * 256 + n];

    float w24 = g1w[24 * 256 + n], w25 = g1w[25 * 256 + n];
    float w50 = g1w[50 * 256 + n], w51 = g1w[51 * 256 + n];
    float accA[16], accC[16];
    #pragma unroll
    for (int t = 0; t < 16; ++t) {
      int j = jg + t;
      // faithful to (a/d - d/2)/(d/2.0) float arithmetic, d=8 (exact pow2 ops)
      float cx = ((float)j * 0.125f - 4.0f) * 0.25f;
      float cy = ((float)(j & 7) - 4.0f) * 0.25f;
      accA[t] = cx * w24 + cy * w25;
      accC[t] = accQ + cx * w50 + cy * w51;
    }
    for (int c = 0; c < 24; ++c) {
      float wa = g1w[c * 256 + n];
      float wc = g1w[(26 + c) * 256 + n];
      const float* xc = x + (b * 24 + c) * 64 + jg;
      #pragma unroll
      for (int t = 0; t < 16; ++t) {
        float xv = xc[t];   // uniform per thread -> scalar load
        accA[t] += xv * wa;
        accC[t] += xv * wc;
      }
    }
    // A in fragment-linear order: j = jt*16 + t (jt = blk&3, r = t), k = n.
    int jt = blk & 3;
    int itA = n >> 5, qA = (n >> 3) & 3, eA = n & 7;
    int baseA = b * 16384 + (jt * 8 + itA) * 512 + qA * 128 + eA;
    #pragma unroll
    for (int t = 0; t < 16; ++t) {
      Ap[baseA + t * 8] = accA[t];
      C[(b * 64 + jg + t) * 256 + n] = accC[t];
    }
  } else {
    // LDS-tiled transpose: g2/g3/g4 [in(k)][out(no)] f32 -> bf16 fragment
    // layout: element (no,k) -> [(no>>4)*8 + (k>>5)][((k>>3)&3)*16 + (no&15)][k&7]
    int t   = blk - 256;
    int mat = t >> 4;                 // 0..2
    int tl  = t & 15;                 // 4x4 tiles of 64x64
    int kt  = (tl & 3) * 64;
    int nt_ = (tl >> 2) * 64;
    const float* W = (mat == 0) ? g2w : (mat == 1 ? g3w : g4w);
    int lane = n & 63, w = n >> 6;
    #pragma unroll
    for (int it = 0; it < 16; ++it) {
      int kl = w * 16 + it;
      T[kl][lane] = W[(kt + kl) * 256 + nt_ + lane];   // coalesced 256B/wave
    }
    __syncthreads();
    #pragma unroll
    for (int it = 0; it < 16; ++it) {
      int nl  = w * 16 + it;
      int no  = nt_ + nl;     // output-neuron index
      int k   = kt + lane;    // input index
      int tile = no >> 4, rr = no & 15;
      int ksI  = k >> 5,  qI = (k >> 3) & 3, e = k & 7;
      int idx  = ((tile * 8 + ksI) * 64 + qI * 16 + rr) * 8 + e;
      Wt[mat * 65536 + idx] = (bf16_t)T[lane][nl];
    }
  }
}

// ---------------- main fused g-MLP (layers 2..4) + pair partial-sum --------
// one block per (b, i): M = 64 rows, N = K = 256, 4 waves.
// Wave w owns n-rows [w*64, w*64+64) (nt=0..3) and all 64 m-rows (mt=0..3).
// Per ks: 4 wf global (1 KB coalesced, L2-shared) + 4 hf LDS -> 16 MFMA.
// Ping-pong: build->hA; L0 reads hA writes hB; L1 reads hB writes hA;
// L2 reads hA -> partial store.  Barriers only at buffer handoffs (3 total).
__global__ __launch_bounds__(256, 2) void rn_main_kernel(
    const float* __restrict__ Ap, const float* __restrict__ C,
    const bf16_t* __restrict__ Wt,
    const float* __restrict__ g2b, const float* __restrict__ g3b,
    const float* __restrict__ g4b,
    float* __restrict__ part)
{
  __shared__ bf16_t hA[16384];   // 32 KB: [chunk=mt*8+ks][lane][8]
  __shared__ bf16_t hB[16384];   // 32 KB

  int tid  = threadIdx.x;
  int bx0  = blockIdx.x;
  // bijective XCD swizzle (4096 % 8 == 0): 512 consecutive work-units per
  // XCD -> the 64 blocks sharing a batch b stay on one XCD's L2
  int bx   = (bx0 & 7) * 512 + (bx0 >> 3);
  int b    = bx >> 6;          // batch
  int i    = bx & 63;          // i-object
  int lane = tid & 63;
  int wave = tid >> 6;
  int r    = lane & 15;        // 16-dim index within MFMA tile
  int q    = lane >> 4;        // quad: k-run selector / D-row group

  // ---- build h rows into hA (fragment-linear) ----
  // wave w builds chunks (mt=w, ks=it).  Ap is pre-arranged so the A read is
  // lane-contiguous; C row i is a cheap broadcast.
  {
    const float* Apb = Ap + (size_t)b * 16384 + wave * 4096;
    const float* Cr  = C + ((size_t)b * 64 + i) * 256;
    #pragma unroll
    for (int it = 0; it < 8; ++it) {
      int k0 = it * 32 + q * 8;
      const float4 a0 = *(const float4*)(Apb + it * 512 + lane * 8);
      const float4 a1 = *(const float4*)(Apb + it * 512 + lane * 8 + 4);
      const float4 c0 = *(const float4*)(Cr + k0);
      const float4 c1 = *(const float4*)(Cr + k0 + 4);
      bf16x8 v;
      v[0] = (bf16_t)fmaxf(a0.x + c0.x, 0.f);
      v[1] = (bf16_t)fmaxf(a0.y + c0.y, 0.f);
      v[2] = (bf16_t)fmaxf(a0.z + c0.z, 0.f);
      v[3] = (bf16_t)fmaxf(a0.w + c0.w, 0.f);
      v[4] = (bf16_t)fmaxf(a1.x + c1.x, 0.f);
      v[5] = (bf16_t)fmaxf(a1.y + c1.y, 0.f);
      v[6] = (bf16_t)fmaxf(a1.z + c1.z, 0.f);
      v[7] = (bf16_t)fmaxf(a1.w + c1.w, 0.f);
      *(bf16x8*)&hA[((wave * 8 + it) * 64 + lane) * 8] = v;
    }
  }
  __syncthreads();             // hA complete

  #pragma unroll
  for (int L = 0; L < 3; ++L) {
    const bf16_t* hs = (L == 1) ? hB : hA;   // compile-time under unroll
    bf16_t*       hd = (L == 0) ? hB : hA;
    const bf16_t* Wl   = Wt + L * 65536 + wave * 16384;
    const float*  bias = (L == 0) ? g2b : (L == 1) ? g3b : g4b;

    f32x4 acc[4][4];           // [nt][mt]
    #pragma unroll
    for (int nt = 0; nt < 4; ++nt)
      #pragma unroll
      for (int mt = 0; mt < 4; ++mt)
        #pragma unroll
        for (int e = 0; e < 4; ++e) acc[nt][mt][e] = 0.f;

    #pragma unroll
    for (int ks = 0; ks < 8; ++ks) {
      bf16x8 wf[4], hf[4];
      #pragma unroll
      for (int nt = 0; nt < 4; ++nt)
        wf[nt] = *(const bf16x8*)&Wl[((nt * 8 + ks) * 64 + lane) * 8];
      #pragma unroll
      for (int mt = 0; mt < 4; ++mt)
        hf[mt] = *(const bf16x8*)&hs[((mt * 8 + ks) * 64 + lane) * 8];
      __builtin_amdgcn_s_setprio(1);
      #pragma unroll
      for (int nt = 0; nt < 4; ++nt)
        #pragma unroll
        for (int mt = 0; mt < 4; ++mt)
          acc[nt][mt] = __builtin_amdgcn_mfma_f32_16x16x32_bf16(
              wf[nt], hf[mt], acc[nt][mt], 0, 0, 0);
      __builtin_amdgcn_s_setprio(0);
    }
    // NO barrier here: reads were from hs, writes go to hd (disjoint).

    if (L < 2) {
      // D value (nt,mt,e): n = wave*64+nt*16+q*4+e (next layer's k),
      // m = mt*16+r.  Fragment-linear write into hd.
      #pragma unroll
      for (int nt = 0; nt < 4; ++nt) {
        int k0  = wave * 64 + nt * 16 + q * 4;
        float4 bv = *(const float4*)&bias[k0];
        int ks_ = k0 >> 5, rem = k0 & 31;
        int qp  = rem >> 3, e0 = rem & 7;     // e0 in {0,4}
        #pragma unroll
        for (int mt = 0; mt < 4; ++mt) {
          bf16x4 v;
          v[0] = (bf16_t)fmaxf(acc[nt][mt][0] + bv.x, 0.f);
          v[1] = (bf16_t)fmaxf(acc[nt][mt][1] + bv.y, 0.f);
          v[2] = (bf16_t)fmaxf(acc[nt][mt][2] + bv.z, 0.f);
          v[3] = (bf16_t)fmaxf(acc[nt][mt][3] + bv.w, 0.f);
          int off = ((mt * 8 + ks_) * 64 + qp * 16 + r) * 8 + e0;
          *(bf16x4*)&hd[off] = v;
        }
      }
      __syncthreads();         // hd complete before next layer reads it
    } else {
      // last layer: bias+relu fp32, sum over the 64 m-rows (mt in-register,
      // then the 16 r-lanes), plain float4 partial store (no atomics).
      #pragma unroll
      for (int nt = 0; nt < 4; ++nt) {
        int k0 = wave * 64 + nt * 16 + q * 4;
        float4 bv = *(const float4*)&bias[k0];
        float p0 = 0.f, p1 = 0.f, p2 = 0.f, p3 = 0.f;
        #pragma unroll
        for (int mt = 0; mt < 4; ++mt) {
          p0 += fmaxf(acc[nt][mt][0] + bv.x, 0.f);
          p1 += fmaxf(acc[nt][mt][1] + bv.y, 0.f);
          p2 += fmaxf(acc[nt][mt][2] + bv.z, 0.f);
          p3 += fmaxf(acc[nt][mt][3] + bv.w, 0.f);
        }
        #pragma unroll
        for (int d = 1; d < 16; d <<= 1) {
          p0 += __shfl_xor(p0, d, 64);
          p1 += __shfl_xor(p1, d, 64);
          p2 += __shfl_xor(p2, d, 64);
          p3 += __shfl_xor(p3, d, 64);
        }
        if (r == 0) {
          float4 pv = make_float4(p0, p1, p2, p3);
          *(float4*)&part[(size_t)bx * 256 + k0] = pv;
        }
      }
    }
  }
}

// ---------------- partial reduce + f-MLP + log_softmax (tiny, fp32) --------
__global__ __launch_bounds__(256) void rn_f_kernel(
    const float* __restrict__ part,
    const float* __restrict__ f1w, const float* __restrict__ f1b,
    const float* __restrict__ f2w, const float* __restrict__ f2b,
    const float* __restrict__ f3w, const float* __restrict__ f3b,
    float* __restrict__ out)
{
  __shared__ float xs[256], t1[256], t2[256], lg[28], lse[1];
  int b = blockIdx.x, tid = threadIdx.x;
  // reduce the 64 per-i partials of batch b (coalesced 1 KB/wave per iter)
  float s = 0.f;
  const float* pb = part + (size_t)b * 64 * 256;
  #pragma unroll 8
  for (int i = 0; i < 64; ++i) s += pb[i * 256 + tid];
  xs[tid] = s;
  __syncthreads();
  float acc = f1b[tid];
  for (int k = 0; k < 256; ++k) acc += xs[k] * f1w[k * 256 + tid];
  t1[tid] = fmaxf(acc, 0.f);
  __syncthreads();
  acc = f2b[tid];
  for (int k = 0; k < 256; ++k) acc += t1[k] * f2w[k * 256 + tid];
  t2[tid] = fmaxf(acc, 0.f);
  __syncthreads();
  if (tid < 28) {
    float a2 = f3b[tid];
    for (int k = 0; k < 256; ++k) a2 += t2[k] * f3w[k * 28 + tid];
    lg[tid] = a2;
  }
  __syncthreads();
  if (tid == 0) {
    float m = lg[0];
    for (int j = 1; j < 28; ++j) m = fmaxf(m, lg[j]);
    float se = 0.f;
    for (int j = 0; j < 28; ++j) se += expf(lg[j] - m);
    lse[0] = m + logf(se);
  }
  __syncthreads();
  if (tid < 28) out[b * 28 + tid] = lg[tid] - lse[0];
}

// ---------------------------------------------------------------------------
extern "C" void kernel_launch(void* const* d_in, const int* in_sizes, int n_in,
                              void* d_out, int out_size, void* d_ws, size_t ws_size,
                              hipStream_t stream) {
  (void)in_sizes; (void)n_in; (void)out_size; (void)ws_size;
  const float* x   = (const float*)d_in[0];
  const float* qst = (const float*)d_in[1];
  const float* g1w = (const float*)d_in[2];
  const float* g1b = (const float*)d_in[3];
  const float* g2w = (const float*)d_in[4];
  const float* g2b = (const float*)d_in[5];
  const float* g3w = (const float*)d_in[6];
  const float* g3b = (const float*)d_in[7];
  const float* g4w = (const float*)d_in[8];
  const float* g4b = (const float*)d_in[9];
  const float* f1w = (const float*)d_in[10];
  const float* f1b = (const float*)d_in[11];
  const float* f2w = (const float*)d_in[12];
  const float* f2b = (const float*)d_in[13];
  const float* f3w = (const float*)d_in[14];
  const float* f3b = (const float*)d_in[15];
  float* out = (float*)d_out;

  float*  Ap   = (float*)d_ws;
  float*  C    = Ap + 4096 * 256;
  bf16_t* Wt   = (bf16_t*)(C + 4096 * 256);
  float*  part = (float*)((char*)Wt + 3 * 65536 * sizeof(bf16_t));

  rn_prep_kernel<<<256 + 48, 256, 0, stream>>>(
      x, qst, g1w, g1b, g2w, g3w, g4w, Ap, C, Wt);
  rn_main_kernel<<<4096, 256, 0, stream>>>(Ap, C, Wt, g2b, g3b, g4b, part);
  rn_f_kernel<<<64, 256, 0, stream>>>(part, f1w, f1b, f2w, f2b, f3w, f3b, out);
}